// Round 15
// baseline (387.456 us; speedup 1.0000x reference)
//
#include <hip/hip_runtime.h>

// FrequencyBandModulation, factored truncated-spectrum form (all bf16 MFMA):
//   W = X*F, D = Hstk*Wstk, V_k = Estk_k*Dstk, low_k = Vstk_k*P_k (per 128x128 image)
//   out = x + d0*x + d1*low1 + d2*low2 + d3*low3   (bf16 delta-gates)
// r15: register-lean fbm targeting combined VGPR+AGPR <= 128 so (512,4)
// compiles spill-free and 2 blocks/CU co-reside:
//   - persistent accumulator = packed-bf16 delta sum (16 regs, was 32 f32)
//   - x*(1+d0) applied at store from L2-hot x re-read
//   - every phase split into sub-passes, peak acc live <= 16 regs

#define NPIX 16384
#define NCHN 256

typedef __attribute__((ext_vector_type(8))) short bf16x8;
typedef __attribute__((ext_vector_type(4))) float f32x4;

__device__ __align__(16) short g_f[64][128];    // W-GEMM B: [n(32R+32I)][q]
__device__ __align__(16) short g_h[192][256];   // D-GEMM A: [dstk][p-stk] (1/128 folded)
__device__ __align__(16) short g_e[3][256][192];// V-GEMM B: [k][mstk][dstk]
__device__ __align__(16) short g_p[3][128][64]; // low-GEMM B: [k][nout][jstk] (1/128 folded)

static __device__ __forceinline__ short f2bf(float f) {
  unsigned u = __float_as_uint(f);
  unsigned r = (u + 0x7fffu + ((u >> 16) & 1u)) >> 16;  // RNE
  return (short)r;
}
static __device__ __forceinline__ float bf2f(short s) {
  return __uint_as_float(((unsigned)(unsigned short)s) << 16);
}
static __device__ __forceinline__ f32x4 mfma16(bf16x8 a, bf16x8 b, f32x4 c) {
  return __builtin_amdgcn_mfma_f32_16x16x32_bf16(a, b, c, 0, 0, 0);
}

// ---------------- constant-table fill (device fn; merged into gates launch) ----------------
static __device__ void const_fill(int idx) {
  const float C = 6.2831853071795864769f / 128.f;
  if (idx < 8192) {                                  // g_f[n][q]
    int n = idx >> 7, q = idx & 127;
    int j = n & 31;
    float ang = C * (float)((j * q) & 127);
    float v = (n < 32) ? cosf(ang) : -sinf(ang);
    reinterpret_cast<short*>(g_f)[idx] = f2bf(v);
  } else if (idx < 57344) {                          // g_h[d][kk]
    int e = idx - 8192;
    int d = e >> 8, kk = e & 255;
    int r = (d < 96) ? d : d - 96;
    int ifr = (r < 32) ? r : r + 32;
    float ang = C * (float)((ifr * (kk & 127)) & 127);
    float cv = cosf(ang) * (1.f / 128.f), sv = sinf(ang) * (1.f / 128.f);
    float v = (d < 96) ? ((kk < 128) ? cv : sv) : ((kk < 128) ? -sv : cv);
    reinterpret_cast<short*>(g_h)[e] = f2bf(v);
  } else if (idx < 204800) {                         // g_e[k][mm][kk]
    int e = idx - 57344;
    int k = e / 49152; int e2 = e % 49152;
    int mm = e2 / 192, kk = e2 % 192;
    int nk = 32 >> k;
    int r = (kk < 96) ? kk : kk - 96;
    bool allow = (r < nk) || (r >= 32);
    int ifr = (r < 32) ? r : r + 32;
    float ang = C * (float)((ifr * (mm & 127)) & 127);
    float cv = cosf(ang), sv = sinf(ang);
    float v = (mm < 128) ? ((kk < 96) ? cv : -sv) : ((kk < 96) ? sv : cv);
    reinterpret_cast<short*>(g_e)[e] = f2bf(allow ? v : 0.f);
  } else if (idx < 229376) {                         // g_p[k][n][jj]
    int e = idx - 204800;
    int k = e / 8192; int e2 = e % 8192;
    int n = e2 >> 6, jj = e2 & 63;
    int nk = 32 >> k;
    int j = jj & 31;
    bool valid = (j < nk) && (jj < 32 || j > 0);
    float wj = (j == 0) ? (1.f / 128.f) : (2.f / 128.f);
    float ang = C * (float)((j * n) & 127);
    float v = (jj < 32) ? (wj * cosf(ang)) : (-wj * sinf(ang));
    reinterpret_cast<short*>(g_p)[e] = f2bf(valid ? v : 0.f);
  }
}

// ---------------- gates partial (+ merged const_init tail blocks) ----------------
__global__ __launch_bounds__(256) void gates_partial_kernel(
    const float* __restrict__ x, const float* __restrict__ Wg,
    float* __restrict__ partial) {
  int bid = blockIdx.x;
  if (bid >= 2048) {                    // const-table duty
    const_fill((bid - 2048) * 256 + threadIdx.x);
    return;
  }
  int b = bid & 7;
  int tile = (bid >> 3) & 63;
  int cs = bid >> 9;
  int m = ((tile >> 3) << 4) + (threadIdx.x >> 4);
  int n = ((tile & 7) << 4) + (threadIdx.x & 15);
  float a0 = 0.f, a1 = 0.f, a2 = 0.f;
  const float* xb = x + (size_t)b * NCHN * NPIX;
  for (int c = cs * 64; c < cs * 64 + 64; ++c) {
    const float* xc = xb + (size_t)c * NPIX;
    const float* wc = Wg + c * 9;
    #pragma unroll
    for (int dh = -1; dh <= 1; ++dh) {
      int gm = m + dh;
      bool vm = (unsigned)gm < 128u;
      #pragma unroll
      for (int dw = -1; dw <= 1; ++dw) {
        int gn = n + dw;
        float xv = (vm && (unsigned)gn < 128u) ? xc[gm * 128 + gn] : 0.f;
        int tap = (dh + 1) * 3 + (dw + 1);
        a0 = fmaf(xv, wc[tap], a0);
        a1 = fmaf(xv, wc[2304 + tap], a1);
        a2 = fmaf(xv, wc[4608 + tap], a2);
      }
    }
  }
  int pix = m * 128 + n;
  float* pp = partial + (size_t)(cs * 8 + b) * 3 * NPIX;
  pp[pix]            = a0;
  pp[NPIX + pix]     = a1;
  pp[2 * NPIX + pix] = a2;
}

__global__ __launch_bounds__(256) void gates_combine_kernel(
    const float* __restrict__ partial, const float* __restrict__ Bg,
    short* __restrict__ dcoef) {
  int bid = blockIdx.x;                 // 512 = 8b * 64
  int b = bid & 7;
  int px = (bid >> 3) * 256 + threadIdx.x;
  float a0 = Bg[0], a1 = Bg[1], a2 = Bg[2];
  #pragma unroll
  for (int cs = 0; cs < 4; ++cs) {
    const float* pp = partial + (size_t)(cs * 8 + b) * 3 * NPIX;
    a0 += pp[px];
    a1 += pp[NPIX + px];
    a2 += pp[2 * NPIX + px];
  }
  float g1 = 2.f / (1.f + expf(-a0));
  float g2 = 2.f / (1.f + expf(-a1));
  float g3 = 2.f / (1.f + expf(-a2));
  int pix = b * NPIX + px;
  dcoef[pix]          = f2bf(g1 - 1.f);
  dcoef[131072 + pix] = f2bf(g2 - g1);
  dcoef[262144 + pix] = f2bf(g3 - g2);
  dcoef[393216 + pix] = f2bf(1.f - g3);
}

// ---------------- fallback gates (if ws too small for partials) ----------------
__global__ __launch_bounds__(256) void gates_kernel(
    const float* __restrict__ x, const float* __restrict__ Wg,
    const float* __restrict__ Bg, short* __restrict__ dcoef) {
  int blk = blockIdx.x;
  if (blk >= 512) {
    const_fill((blk - 512) * 256 + threadIdx.x);
    return;
  }
  int b = blk >> 6;
  int tile = blk & 63;
  int m = ((tile >> 3) << 4) + (threadIdx.x >> 4);
  int n = ((tile & 7) << 4) + (threadIdx.x & 15);
  float a0 = 0.f, a1 = 0.f, a2 = 0.f;
  const float* xb = x + (size_t)b * NCHN * NPIX;
  for (int c = 0; c < NCHN; ++c) {
    const float* xc = xb + (size_t)c * NPIX;
    const float* wc = Wg + c * 9;
    #pragma unroll
    for (int dh = -1; dh <= 1; ++dh) {
      int gm = m + dh;
      bool vm = (unsigned)gm < 128u;
      #pragma unroll
      for (int dw = -1; dw <= 1; ++dw) {
        int gn = n + dw;
        float xv = (vm && (unsigned)gn < 128u) ? xc[gm * 128 + gn] : 0.f;
        int tap = (dh + 1) * 3 + (dw + 1);
        a0 = fmaf(xv, wc[tap], a0);
        a1 = fmaf(xv, wc[2304 + tap], a1);
        a2 = fmaf(xv, wc[4608 + tap], a2);
      }
    }
  }
  a0 += Bg[0]; a1 += Bg[1]; a2 += Bg[2];
  float g1 = 2.f / (1.f + expf(-a0));
  float g2 = 2.f / (1.f + expf(-a1));
  float g3 = 2.f / (1.f + expf(-a2));
  int pix = b * NPIX + m * 128 + n;
  dcoef[pix]          = f2bf(g1 - 1.f);
  dcoef[131072 + pix] = f2bf(g2 - g1);
  dcoef[262144 + pix] = f2bf(g3 - g2);
  dcoef[393216 + pix] = f2bf(1.f - g3);
}

// ---------------- fused spectral kernel: 4 channels of one b per block ----------------
// 512 threads, 60 KB LDS, register-lean body, (512,4) for 2 blocks/CU.
__global__ __launch_bounds__(512, 4) void fbm_kernel(
    const float* __restrict__ x, const short* __restrict__ dcoef,
    float* __restrict__ out) {
  __shared__ __align__(16) short Xs[16384];      // 32 KB: X bf16 / low plane (aliased)
  __shared__ __align__(16) short WVs[8192];      // 16 KB: W^T / V^T
  __shared__ __align__(16) short Ds2[6144];      // 12 KB: D^T [32n][192dstk]
  char* XsB = reinterpret_cast<char*>(Xs);
  char* PlaneB = XsB;
  char* WsB = reinterpret_cast<char*>(WVs);
  char* DsB = reinterpret_cast<char*>(Ds2);

  int t = threadIdx.x;
  int bid = blockIdx.x;                 // 512 blocks
  int b = bid >> 6;
  int cg = bid & 63;
  size_t img0 = ((size_t)b << 8) + ((size_t)cg << 2);
  int lane = t & 63, w = t >> 6;
  int l15 = lane & 15, l4 = lane >> 4;
  const f32x4 zero = {0.f, 0.f, 0.f, 0.f};

  const short4* d0p = reinterpret_cast<const short4*>(dcoef + ((size_t)b << 14));

  for (int c = 0; c < 4; ++c) {
    // ---- persistent delta accumulator: 32 pixels packed bf16 (16 regs) ----
    unsigned dacc[16];
    #pragma unroll
    for (int i = 0; i < 16; ++i) dacc[i] = 0u;

    // ---- init: stage bf16 X into Xs (x cached for store re-read) ----
    {
      const f32x4* xv4 = reinterpret_cast<const f32x4*>(x + (img0 + c) * NPIX);
      #pragma unroll
      for (int i = 0; i < 8; ++i) {
        int f = t + i * 512;
        f32x4 xv = xv4[f];
        int row = f >> 5;
        int byte = row * 256 + (((f & 31) * 8) ^ ((row & 7) << 4));
        short4 s;
        s.x = f2bf(xv[0]); s.y = f2bf(xv[1]); s.z = f2bf(xv[2]); s.w = f2bf(xv[3]);
        *reinterpret_cast<short4*>(XsB + byte) = s;
      }
    }
    __syncthreads();

    // ---- P0: W = X*F, two sub-passes of 2 M-tiles (acc live = 8 regs) ----
    {
      int Ntile = w & 3, Mq = w >> 2;
      int n = Ntile * 16 + l15;
      #pragma unroll
      for (int h = 0; h < 2; ++h) {
        f32x4 acc[2] = {zero, zero};
        #pragma unroll
        for (int ks = 0; ks < 4; ++ks) {
          int koff = ks * 32 + l4 * 8;
          bf16x8 bf = *reinterpret_cast<const bf16x8*>(&g_f[n][koff]);
          #pragma unroll
          for (int mt = 0; mt < 2; ++mt) {
            int p = (Mq * 4 + h * 2 + mt) * 16 + l15;
            bf16x8 a = *reinterpret_cast<const bf16x8*>(
                XsB + p * 256 + ((koff * 2) ^ ((p & 7) << 4)));
            acc[mt] = mfma16(a, bf, acc[mt]);
          }
        }
        #pragma unroll
        for (int mt = 0; mt < 2; ++mt) {
          int p0 = (Mq * 4 + h * 2 + mt) * 16 + l4 * 4;
          short4 s;
          s.x = f2bf(acc[mt][0]); s.y = f2bf(acc[mt][1]);
          s.z = f2bf(acc[mt][2]); s.w = f2bf(acc[mt][3]);
          *reinterpret_cast<short4*>(WsB + n * 256 + ((p0 * 2) ^ ((n & 7) << 4))) = s;
        }
      }
    }
    __syncthreads();

    // ---- P1: D = Hstk*Wstk, three single-tile passes (acc live = 4 regs) ----
    {
      int Ntile = w & 1, Mt3 = w >> 1;
      int n = Ntile * 16 + l15;
      #pragma unroll
      for (int mt = 0; mt < 3; ++mt) {
        f32x4 acc = zero;
        #pragma unroll
        for (int ks = 0; ks < 8; ++ks) {
          int koff = ks * 32 + l4 * 8;
          int wrow = n + ((ks >= 4) ? 32 : 0);
          bf16x8 bb = *reinterpret_cast<const bf16x8*>(
              WsB + wrow * 256 + (((koff & 127) * 2) ^ ((wrow & 7) << 4)));
          int d = (Mt3 * 3 + mt) * 16 + l15;
          bf16x8 aa = *reinterpret_cast<const bf16x8*>(&g_h[d][koff]);
          acc = mfma16(aa, bb, acc);
        }
        int d0 = (Mt3 * 3 + mt) * 16 + l4 * 4;
        short4 s;
        s.x = f2bf(acc[0]); s.y = f2bf(acc[1]);
        s.z = f2bf(acc[2]); s.w = f2bf(acc[3]);
        *reinterpret_cast<short4*>(DsB + n * 384 + ((d0 * 2) ^ ((n & 7) << 4))) = s;
      }
    }
    __syncthreads();

    int Mg3 = w >> 2, Ng3 = w & 3;
    for (int k = 0; k < 3; ++k) {
      // ---- P2: V_k = Estk_k*Dstk, two j-passes (acc live = 8 regs) ----
      #pragma unroll
      for (int ni = 0; ni < 2; ++ni) {
        f32x4 acc[2] = {zero, zero};
        int jn = ni * 16 + l15;
        #pragma unroll
        for (int ks = 0; ks < 6; ++ks) {
          int koff = ks * 32 + l4 * 8;
          bf16x8 bn = *reinterpret_cast<const bf16x8*>(
              DsB + jn * 384 + ((koff * 2) ^ ((jn & 7) << 4)));
          #pragma unroll
          for (int mi = 0; mi < 2; ++mi) {
            int mstk = (2 * w + mi) * 16 + l15;
            bf16x8 aa = *reinterpret_cast<const bf16x8*>(&g_e[k][mstk][koff]);
            acc[mi] = mfma16(aa, bn, acc[mi]);
          }
        }
        #pragma unroll
        for (int mi = 0; mi < 2; ++mi) {
          #pragma unroll
          for (int r = 0; r < 4; ++r) {
            int mstk = (2 * w + mi) * 16 + l4 * 4 + r;
            int m = mstk & 127;
            int jst = ((mstk >> 7) << 5) + jn;
            *reinterpret_cast<short*>(WsB + m * 128 + ((jst * 2) ^ ((m & 7) << 4))) =
                f2bf(acc[mi][r]);
          }
        }
      }
      __syncthreads();
      // ---- P3: low_k = Vstk*P_k, two nt-passes (acc live = 16 regs) ----
      #pragma unroll
      for (int nt = 0; nt < 2; ++nt) {
        f32x4 acc[4] = {zero, zero, zero, zero};
        int nout = (Ng3 * 2 + nt) * 16 + l15;
        #pragma unroll
        for (int ks = 0; ks < 2; ++ks) {
          int koff = ks * 32 + l4 * 8;
          bf16x8 bfr = *reinterpret_cast<const bf16x8*>(&g_p[k][nout][koff]);
          #pragma unroll
          for (int mt = 0; mt < 4; ++mt) {
            int m = (Mg3 * 4 + mt) * 16 + l15;
            bf16x8 aa = *reinterpret_cast<const bf16x8*>(
                WsB + m * 128 + ((koff * 2) ^ ((m & 7) << 4)));
            acc[mt] = mfma16(aa, bfr, acc[mt]);
          }
        }
        #pragma unroll
        for (int mt = 0; mt < 4; ++mt) {
          #pragma unroll
          for (int r = 0; r < 4; ++r) {
            int row = (Mg3 * 4 + mt) * 16 + l4 * 4 + r;
            int byte = row * 256 + ((nout ^ ((row & 7) << 2)) << 1);
            *reinterpret_cast<short*>(PlaneB + byte) = f2bf(acc[mt][r]);
          }
        }
      }
      __syncthreads();
      // ---- fold: dacc(bf16) += dk * plane_k ----
      {
        const short4* dk = reinterpret_cast<const short4*>(
            dcoef + (size_t)(k + 1) * 131072 + ((size_t)b << 14));
        #pragma unroll
        for (int i = 0; i < 8; ++i) {
          int f = t + i * 512;
          int row = f >> 5;
          int col = (f & 31) * 4;
          int byte = row * 256 + ((col ^ ((row & 7) << 2)) << 1);
          short4 s = *reinterpret_cast<const short4*>(PlaneB + byte);
          short4 dv = dk[f];
          unsigned a0 = dacc[2 * i], a1 = dacc[2 * i + 1];
          float l0 = fmaf(bf2f(dv.x), bf2f(s.x), bf2f((short)(a0 & 0xffff)));
          float l1 = fmaf(bf2f(dv.y), bf2f(s.y), bf2f((short)(a0 >> 16)));
          float l2 = fmaf(bf2f(dv.z), bf2f(s.z), bf2f((short)(a1 & 0xffff)));
          float l3 = fmaf(bf2f(dv.w), bf2f(s.w), bf2f((short)(a1 >> 16)));
          dacc[2 * i] = (unsigned)(unsigned short)f2bf(l0) |
                        ((unsigned)(unsigned short)f2bf(l1) << 16);
          dacc[2 * i + 1] = (unsigned)(unsigned short)f2bf(l2) |
                            ((unsigned)(unsigned short)f2bf(l3) << 16);
        }
      }
      __syncthreads();   // plane (Xs) reads done before next P3 / next-channel init
    }

    // ---- store: out = x*(1+d0) + dacc  (x re-read is L2-hot) ----
    {
      const f32x4* xv4 = reinterpret_cast<const f32x4*>(x + (img0 + c) * NPIX);
      f32x4* og4 = reinterpret_cast<f32x4*>(out + (img0 + c) * NPIX);
      #pragma unroll
      for (int i = 0; i < 8; ++i) {
        int f = t + i * 512;
        f32x4 xv = xv4[f];
        short4 dv = d0p[f];
        unsigned a0 = dacc[2 * i], a1 = dacc[2 * i + 1];
        f32x4 o;
        o[0] = fmaf(bf2f(dv.x), xv[0], xv[0]) + bf2f((short)(a0 & 0xffff));
        o[1] = fmaf(bf2f(dv.y), xv[1], xv[1]) + bf2f((short)(a0 >> 16));
        o[2] = fmaf(bf2f(dv.z), xv[2], xv[2]) + bf2f((short)(a1 & 0xffff));
        o[3] = fmaf(bf2f(dv.w), xv[3], xv[3]) + bf2f((short)(a1 >> 16));
        __builtin_nontemporal_store(o, &og4[f]);
      }
    }
  }
}

extern "C" void kernel_launch(void* const* d_in, const int* in_sizes, int n_in,
                              void* d_out, int out_size, void* d_ws, size_t ws_size,
                              hipStream_t stream) {
  const float* x  = (const float*)d_in[0];
  const float* Wg = (const float*)d_in[1];
  const float* Bg = (const float*)d_in[2];
  float* out  = (float*)d_out;
  short* dcoef = (short*)d_ws;                              // 1 MiB: 4 bf16 planes
  float* partial = (float*)((char*)d_ws + (1u << 20));      // 6 MiB
  if (ws_size >= (size_t)(8u << 20)) {
    gates_partial_kernel<<<2944, 256, 0, stream>>>(x, Wg, partial);  // +896 const blocks
    gates_combine_kernel<<<512, 256, 0, stream>>>(partial, Bg, dcoef);
  } else {
    gates_kernel<<<1408, 256, 0, stream>>>(x, Wg, Bg, dcoef);        // +896 const blocks
  }
  fbm_kernel<<<512, 512, 0, stream>>>(x, dcoef, out);
}

// Round 16
// 359.755 us; speedup vs baseline: 1.0770x; 1.0770x over previous
//
#include <hip/hip_runtime.h>

// FrequencyBandModulation, factored truncated-spectrum form (all bf16 MFMA):
//   W = X*F, D = Hstk*Wstk, V_k = Estk_k*Dstk, low_k = Vstk_k*P_k (per 128x128 image)
//   out = x + d0*x + d1*low1 + d2*low2 + d3*low3   (bf16 delta-gates)
// r16: r15's register-lean body (verified, absmax 0.015625) compiled at
// __launch_bounds__(512,2). Empirical law from r5..r15: VGPR cap = 256/arg;
// (,4) clamped the lean body to 64 and spilled. At (,2) cap=128 the lean
// body's ~100-110 demand fits -> 4 waves/SIMD -> 2 blocks/CU, no spill.

#define NPIX 16384
#define NCHN 256

typedef __attribute__((ext_vector_type(8))) short bf16x8;
typedef __attribute__((ext_vector_type(4))) float f32x4;

__device__ __align__(16) short g_f[64][128];    // W-GEMM B: [n(32R+32I)][q]
__device__ __align__(16) short g_h[192][256];   // D-GEMM A: [dstk][p-stk] (1/128 folded)
__device__ __align__(16) short g_e[3][256][192];// V-GEMM B: [k][mstk][dstk]
__device__ __align__(16) short g_p[3][128][64]; // low-GEMM B: [k][nout][jstk] (1/128 folded)

static __device__ __forceinline__ short f2bf(float f) {
  unsigned u = __float_as_uint(f);
  unsigned r = (u + 0x7fffu + ((u >> 16) & 1u)) >> 16;  // RNE
  return (short)r;
}
static __device__ __forceinline__ float bf2f(short s) {
  return __uint_as_float(((unsigned)(unsigned short)s) << 16);
}
static __device__ __forceinline__ f32x4 mfma16(bf16x8 a, bf16x8 b, f32x4 c) {
  return __builtin_amdgcn_mfma_f32_16x16x32_bf16(a, b, c, 0, 0, 0);
}

// ---------------- constant-table fill (device fn; merged into gates launch) ----------------
static __device__ void const_fill(int idx) {
  const float C = 6.2831853071795864769f / 128.f;
  if (idx < 8192) {                                  // g_f[n][q]
    int n = idx >> 7, q = idx & 127;
    int j = n & 31;
    float ang = C * (float)((j * q) & 127);
    float v = (n < 32) ? cosf(ang) : -sinf(ang);
    reinterpret_cast<short*>(g_f)[idx] = f2bf(v);
  } else if (idx < 57344) {                          // g_h[d][kk]
    int e = idx - 8192;
    int d = e >> 8, kk = e & 255;
    int r = (d < 96) ? d : d - 96;
    int ifr = (r < 32) ? r : r + 32;
    float ang = C * (float)((ifr * (kk & 127)) & 127);
    float cv = cosf(ang) * (1.f / 128.f), sv = sinf(ang) * (1.f / 128.f);
    float v = (d < 96) ? ((kk < 128) ? cv : sv) : ((kk < 128) ? -sv : cv);
    reinterpret_cast<short*>(g_h)[e] = f2bf(v);
  } else if (idx < 204800) {                         // g_e[k][mm][kk]
    int e = idx - 57344;
    int k = e / 49152; int e2 = e % 49152;
    int mm = e2 / 192, kk = e2 % 192;
    int nk = 32 >> k;
    int r = (kk < 96) ? kk : kk - 96;
    bool allow = (r < nk) || (r >= 32);
    int ifr = (r < 32) ? r : r + 32;
    float ang = C * (float)((ifr * (mm & 127)) & 127);
    float cv = cosf(ang), sv = sinf(ang);
    float v = (mm < 128) ? ((kk < 96) ? cv : -sv) : ((kk < 96) ? sv : cv);
    reinterpret_cast<short*>(g_e)[e] = f2bf(allow ? v : 0.f);
  } else if (idx < 229376) {                         // g_p[k][n][jj]
    int e = idx - 204800;
    int k = e / 8192; int e2 = e % 8192;
    int n = e2 >> 6, jj = e2 & 63;
    int nk = 32 >> k;
    int j = jj & 31;
    bool valid = (j < nk) && (jj < 32 || j > 0);
    float wj = (j == 0) ? (1.f / 128.f) : (2.f / 128.f);
    float ang = C * (float)((j * n) & 127);
    float v = (jj < 32) ? (wj * cosf(ang)) : (-wj * sinf(ang));
    reinterpret_cast<short*>(g_p)[e] = f2bf(valid ? v : 0.f);
  }
}

// ---------------- gates partial (+ merged const_init tail blocks) ----------------
__global__ __launch_bounds__(256) void gates_partial_kernel(
    const float* __restrict__ x, const float* __restrict__ Wg,
    float* __restrict__ partial) {
  int bid = blockIdx.x;
  if (bid >= 2048) {                    // const-table duty
    const_fill((bid - 2048) * 256 + threadIdx.x);
    return;
  }
  int b = bid & 7;
  int tile = (bid >> 3) & 63;
  int cs = bid >> 9;
  int m = ((tile >> 3) << 4) + (threadIdx.x >> 4);
  int n = ((tile & 7) << 4) + (threadIdx.x & 15);
  float a0 = 0.f, a1 = 0.f, a2 = 0.f;
  const float* xb = x + (size_t)b * NCHN * NPIX;
  for (int c = cs * 64; c < cs * 64 + 64; ++c) {
    const float* xc = xb + (size_t)c * NPIX;
    const float* wc = Wg + c * 9;
    #pragma unroll
    for (int dh = -1; dh <= 1; ++dh) {
      int gm = m + dh;
      bool vm = (unsigned)gm < 128u;
      #pragma unroll
      for (int dw = -1; dw <= 1; ++dw) {
        int gn = n + dw;
        float xv = (vm && (unsigned)gn < 128u) ? xc[gm * 128 + gn] : 0.f;
        int tap = (dh + 1) * 3 + (dw + 1);
        a0 = fmaf(xv, wc[tap], a0);
        a1 = fmaf(xv, wc[2304 + tap], a1);
        a2 = fmaf(xv, wc[4608 + tap], a2);
      }
    }
  }
  int pix = m * 128 + n;
  float* pp = partial + (size_t)(cs * 8 + b) * 3 * NPIX;
  pp[pix]            = a0;
  pp[NPIX + pix]     = a1;
  pp[2 * NPIX + pix] = a2;
}

__global__ __launch_bounds__(256) void gates_combine_kernel(
    const float* __restrict__ partial, const float* __restrict__ Bg,
    short* __restrict__ dcoef) {
  int bid = blockIdx.x;                 // 512 = 8b * 64
  int b = bid & 7;
  int px = (bid >> 3) * 256 + threadIdx.x;
  float a0 = Bg[0], a1 = Bg[1], a2 = Bg[2];
  #pragma unroll
  for (int cs = 0; cs < 4; ++cs) {
    const float* pp = partial + (size_t)(cs * 8 + b) * 3 * NPIX;
    a0 += pp[px];
    a1 += pp[NPIX + px];
    a2 += pp[2 * NPIX + px];
  }
  float g1 = 2.f / (1.f + expf(-a0));
  float g2 = 2.f / (1.f + expf(-a1));
  float g3 = 2.f / (1.f + expf(-a2));
  int pix = b * NPIX + px;
  dcoef[pix]          = f2bf(g1 - 1.f);
  dcoef[131072 + pix] = f2bf(g2 - g1);
  dcoef[262144 + pix] = f2bf(g3 - g2);
  dcoef[393216 + pix] = f2bf(1.f - g3);
}

// ---------------- fallback gates (if ws too small for partials) ----------------
__global__ __launch_bounds__(256) void gates_kernel(
    const float* __restrict__ x, const float* __restrict__ Wg,
    const float* __restrict__ Bg, short* __restrict__ dcoef) {
  int blk = blockIdx.x;
  if (blk >= 512) {
    const_fill((blk - 512) * 256 + threadIdx.x);
    return;
  }
  int b = blk >> 6;
  int tile = blk & 63;
  int m = ((tile >> 3) << 4) + (threadIdx.x >> 4);
  int n = ((tile & 7) << 4) + (threadIdx.x & 15);
  float a0 = 0.f, a1 = 0.f, a2 = 0.f;
  const float* xb = x + (size_t)b * NCHN * NPIX;
  for (int c = 0; c < NCHN; ++c) {
    const float* xc = xb + (size_t)c * NPIX;
    const float* wc = Wg + c * 9;
    #pragma unroll
    for (int dh = -1; dh <= 1; ++dh) {
      int gm = m + dh;
      bool vm = (unsigned)gm < 128u;
      #pragma unroll
      for (int dw = -1; dw <= 1; ++dw) {
        int gn = n + dw;
        float xv = (vm && (unsigned)gn < 128u) ? xc[gm * 128 + gn] : 0.f;
        int tap = (dh + 1) * 3 + (dw + 1);
        a0 = fmaf(xv, wc[tap], a0);
        a1 = fmaf(xv, wc[2304 + tap], a1);
        a2 = fmaf(xv, wc[4608 + tap], a2);
      }
    }
  }
  a0 += Bg[0]; a1 += Bg[1]; a2 += Bg[2];
  float g1 = 2.f / (1.f + expf(-a0));
  float g2 = 2.f / (1.f + expf(-a1));
  float g3 = 2.f / (1.f + expf(-a2));
  int pix = b * NPIX + m * 128 + n;
  dcoef[pix]          = f2bf(g1 - 1.f);
  dcoef[131072 + pix] = f2bf(g2 - g1);
  dcoef[262144 + pix] = f2bf(g3 - g2);
  dcoef[393216 + pix] = f2bf(1.f - g3);
}

// ---------------- fused spectral kernel: 4 channels of one b per block ----------------
// 512 threads, 60 KB LDS, register-lean body, (512,2): cap 128, lean demand fits.
__global__ __launch_bounds__(512, 2) void fbm_kernel(
    const float* __restrict__ x, const short* __restrict__ dcoef,
    float* __restrict__ out) {
  __shared__ __align__(16) short Xs[16384];      // 32 KB: X bf16 / low plane (aliased)
  __shared__ __align__(16) short WVs[8192];      // 16 KB: W^T / V^T
  __shared__ __align__(16) short Ds2[6144];      // 12 KB: D^T [32n][192dstk]
  char* XsB = reinterpret_cast<char*>(Xs);
  char* PlaneB = XsB;
  char* WsB = reinterpret_cast<char*>(WVs);
  char* DsB = reinterpret_cast<char*>(Ds2);

  int t = threadIdx.x;
  int bid = blockIdx.x;                 // 512 blocks
  int b = bid >> 6;
  int cg = bid & 63;
  size_t img0 = ((size_t)b << 8) + ((size_t)cg << 2);
  int lane = t & 63, w = t >> 6;
  int l15 = lane & 15, l4 = lane >> 4;
  const f32x4 zero = {0.f, 0.f, 0.f, 0.f};

  const short4* d0p = reinterpret_cast<const short4*>(dcoef + ((size_t)b << 14));

  for (int c = 0; c < 4; ++c) {
    // ---- persistent delta accumulator: 32 pixels packed bf16 (16 regs) ----
    unsigned dacc[16];
    #pragma unroll
    for (int i = 0; i < 16; ++i) dacc[i] = 0u;

    // ---- init: stage bf16 X into Xs (x cached for store re-read) ----
    {
      const f32x4* xv4 = reinterpret_cast<const f32x4*>(x + (img0 + c) * NPIX);
      #pragma unroll
      for (int i = 0; i < 8; ++i) {
        int f = t + i * 512;
        f32x4 xv = xv4[f];
        int row = f >> 5;
        int byte = row * 256 + (((f & 31) * 8) ^ ((row & 7) << 4));
        short4 s;
        s.x = f2bf(xv[0]); s.y = f2bf(xv[1]); s.z = f2bf(xv[2]); s.w = f2bf(xv[3]);
        *reinterpret_cast<short4*>(XsB + byte) = s;
      }
    }
    __syncthreads();

    // ---- P0: W = X*F, two sub-passes of 2 M-tiles (acc live = 8 regs) ----
    {
      int Ntile = w & 3, Mq = w >> 2;
      int n = Ntile * 16 + l15;
      #pragma unroll
      for (int h = 0; h < 2; ++h) {
        f32x4 acc[2] = {zero, zero};
        #pragma unroll
        for (int ks = 0; ks < 4; ++ks) {
          int koff = ks * 32 + l4 * 8;
          bf16x8 bf = *reinterpret_cast<const bf16x8*>(&g_f[n][koff]);
          #pragma unroll
          for (int mt = 0; mt < 2; ++mt) {
            int p = (Mq * 4 + h * 2 + mt) * 16 + l15;
            bf16x8 a = *reinterpret_cast<const bf16x8*>(
                XsB + p * 256 + ((koff * 2) ^ ((p & 7) << 4)));
            acc[mt] = mfma16(a, bf, acc[mt]);
          }
        }
        #pragma unroll
        for (int mt = 0; mt < 2; ++mt) {
          int p0 = (Mq * 4 + h * 2 + mt) * 16 + l4 * 4;
          short4 s;
          s.x = f2bf(acc[mt][0]); s.y = f2bf(acc[mt][1]);
          s.z = f2bf(acc[mt][2]); s.w = f2bf(acc[mt][3]);
          *reinterpret_cast<short4*>(WsB + n * 256 + ((p0 * 2) ^ ((n & 7) << 4))) = s;
        }
      }
    }
    __syncthreads();

    // ---- P1: D = Hstk*Wstk, three single-tile passes (acc live = 4 regs) ----
    {
      int Ntile = w & 1, Mt3 = w >> 1;
      int n = Ntile * 16 + l15;
      #pragma unroll
      for (int mt = 0; mt < 3; ++mt) {
        f32x4 acc = zero;
        #pragma unroll
        for (int ks = 0; ks < 8; ++ks) {
          int koff = ks * 32 + l4 * 8;
          int wrow = n + ((ks >= 4) ? 32 : 0);
          bf16x8 bb = *reinterpret_cast<const bf16x8*>(
              WsB + wrow * 256 + (((koff & 127) * 2) ^ ((wrow & 7) << 4)));
          int d = (Mt3 * 3 + mt) * 16 + l15;
          bf16x8 aa = *reinterpret_cast<const bf16x8*>(&g_h[d][koff]);
          acc = mfma16(aa, bb, acc);
        }
        int d0 = (Mt3 * 3 + mt) * 16 + l4 * 4;
        short4 s;
        s.x = f2bf(acc[0]); s.y = f2bf(acc[1]);
        s.z = f2bf(acc[2]); s.w = f2bf(acc[3]);
        *reinterpret_cast<short4*>(DsB + n * 384 + ((d0 * 2) ^ ((n & 7) << 4))) = s;
      }
    }
    __syncthreads();

    int Mg3 = w >> 2, Ng3 = w & 3;
    for (int k = 0; k < 3; ++k) {
      // ---- P2: V_k = Estk_k*Dstk, two j-passes (acc live = 8 regs) ----
      #pragma unroll
      for (int ni = 0; ni < 2; ++ni) {
        f32x4 acc[2] = {zero, zero};
        int jn = ni * 16 + l15;
        #pragma unroll
        for (int ks = 0; ks < 6; ++ks) {
          int koff = ks * 32 + l4 * 8;
          bf16x8 bn = *reinterpret_cast<const bf16x8*>(
              DsB + jn * 384 + ((koff * 2) ^ ((jn & 7) << 4)));
          #pragma unroll
          for (int mi = 0; mi < 2; ++mi) {
            int mstk = (2 * w + mi) * 16 + l15;
            bf16x8 aa = *reinterpret_cast<const bf16x8*>(&g_e[k][mstk][koff]);
            acc[mi] = mfma16(aa, bn, acc[mi]);
          }
        }
        #pragma unroll
        for (int mi = 0; mi < 2; ++mi) {
          #pragma unroll
          for (int r = 0; r < 4; ++r) {
            int mstk = (2 * w + mi) * 16 + l4 * 4 + r;
            int m = mstk & 127;
            int jst = ((mstk >> 7) << 5) + jn;
            *reinterpret_cast<short*>(WsB + m * 128 + ((jst * 2) ^ ((m & 7) << 4))) =
                f2bf(acc[mi][r]);
          }
        }
      }
      __syncthreads();
      // ---- P3: low_k = Vstk*P_k, two nt-passes (acc live = 16 regs) ----
      #pragma unroll
      for (int nt = 0; nt < 2; ++nt) {
        f32x4 acc[4] = {zero, zero, zero, zero};
        int nout = (Ng3 * 2 + nt) * 16 + l15;
        #pragma unroll
        for (int ks = 0; ks < 2; ++ks) {
          int koff = ks * 32 + l4 * 8;
          bf16x8 bfr = *reinterpret_cast<const bf16x8*>(&g_p[k][nout][koff]);
          #pragma unroll
          for (int mt = 0; mt < 4; ++mt) {
            int m = (Mg3 * 4 + mt) * 16 + l15;
            bf16x8 aa = *reinterpret_cast<const bf16x8*>(
                WsB + m * 128 + ((koff * 2) ^ ((m & 7) << 4)));
            acc[mt] = mfma16(aa, bfr, acc[mt]);
          }
        }
        #pragma unroll
        for (int mt = 0; mt < 4; ++mt) {
          #pragma unroll
          for (int r = 0; r < 4; ++r) {
            int row = (Mg3 * 4 + mt) * 16 + l4 * 4 + r;
            int byte = row * 256 + ((nout ^ ((row & 7) << 2)) << 1);
            *reinterpret_cast<short*>(PlaneB + byte) = f2bf(acc[mt][r]);
          }
        }
      }
      __syncthreads();
      // ---- fold: dacc(bf16) += dk * plane_k ----
      {
        const short4* dk = reinterpret_cast<const short4*>(
            dcoef + (size_t)(k + 1) * 131072 + ((size_t)b << 14));
        #pragma unroll
        for (int i = 0; i < 8; ++i) {
          int f = t + i * 512;
          int row = f >> 5;
          int col = (f & 31) * 4;
          int byte = row * 256 + ((col ^ ((row & 7) << 2)) << 1);
          short4 s = *reinterpret_cast<const short4*>(PlaneB + byte);
          short4 dv = dk[f];
          unsigned a0 = dacc[2 * i], a1 = dacc[2 * i + 1];
          float l0 = fmaf(bf2f(dv.x), bf2f(s.x), bf2f((short)(a0 & 0xffff)));
          float l1 = fmaf(bf2f(dv.y), bf2f(s.y), bf2f((short)(a0 >> 16)));
          float l2 = fmaf(bf2f(dv.z), bf2f(s.z), bf2f((short)(a1 & 0xffff)));
          float l3 = fmaf(bf2f(dv.w), bf2f(s.w), bf2f((short)(a1 >> 16)));
          dacc[2 * i] = (unsigned)(unsigned short)f2bf(l0) |
                        ((unsigned)(unsigned short)f2bf(l1) << 16);
          dacc[2 * i + 1] = (unsigned)(unsigned short)f2bf(l2) |
                            ((unsigned)(unsigned short)f2bf(l3) << 16);
        }
      }
      __syncthreads();   // plane (Xs) reads done before next P3 / next-channel init
    }

    // ---- store: out = x*(1+d0) + dacc  (x re-read is L2-hot) ----
    {
      const f32x4* xv4 = reinterpret_cast<const f32x4*>(x + (img0 + c) * NPIX);
      f32x4* og4 = reinterpret_cast<f32x4*>(out + (img0 + c) * NPIX);
      #pragma unroll
      for (int i = 0; i < 8; ++i) {
        int f = t + i * 512;
        f32x4 xv = xv4[f];
        short4 dv = d0p[f];
        unsigned a0 = dacc[2 * i], a1 = dacc[2 * i + 1];
        f32x4 o;
        o[0] = fmaf(bf2f(dv.x), xv[0], xv[0]) + bf2f((short)(a0 & 0xffff));
        o[1] = fmaf(bf2f(dv.y), xv[1], xv[1]) + bf2f((short)(a0 >> 16));
        o[2] = fmaf(bf2f(dv.z), xv[2], xv[2]) + bf2f((short)(a1 & 0xffff));
        o[3] = fmaf(bf2f(dv.w), xv[3], xv[3]) + bf2f((short)(a1 >> 16));
        __builtin_nontemporal_store(o, &og4[f]);
      }
    }
  }
}

extern "C" void kernel_launch(void* const* d_in, const int* in_sizes, int n_in,
                              void* d_out, int out_size, void* d_ws, size_t ws_size,
                              hipStream_t stream) {
  const float* x  = (const float*)d_in[0];
  const float* Wg = (const float*)d_in[1];
  const float* Bg = (const float*)d_in[2];
  float* out  = (float*)d_out;
  short* dcoef = (short*)d_ws;                              // 1 MiB: 4 bf16 planes
  float* partial = (float*)((char*)d_ws + (1u << 20));      // 6 MiB
  if (ws_size >= (size_t)(8u << 20)) {
    gates_partial_kernel<<<2944, 256, 0, stream>>>(x, Wg, partial);  // +896 const blocks
    gates_combine_kernel<<<512, 256, 0, stream>>>(partial, Bg, dcoef);
  } else {
    gates_kernel<<<1408, 256, 0, stream>>>(x, Wg, Bg, dcoef);        // +896 const blocks
  }
  fbm_kernel<<<512, 512, 0, stream>>>(x, dcoef, out);
}

// Round 17
// 302.025 us; speedup vs baseline: 1.2829x; 1.1911x over previous
//
#include <hip/hip_runtime.h>

// FrequencyBandModulation, factored truncated-spectrum form (all bf16 MFMA):
//   W = X*F, D = Hstk*Wstk, V_k = Estk_k*Dstk, low_k = Vstk_k*P_k (per 128x128 image)
//   out = x + d0*x + d1*low1 + d2*low2 + d3*low3   (bf16 delta-gates)
// r17: r14 body (best verified: fbm 240us, VGPR 116, clean traffic) with
//   (1) post-fold barrier removed (fold || next P2 — disjoint LDS regions;
//       PlaneB overwrite fenced by the post-P2 barrier): 12 -> 10 gens/channel
//   (2) 8-way gates channel split when ws allows (fallback 4-way / monolithic)

#define NPIX 16384
#define NCHN 256

typedef __attribute__((ext_vector_type(8))) short bf16x8;
typedef __attribute__((ext_vector_type(4))) float f32x4;

__device__ __align__(16) short g_f[64][128];    // W-GEMM B: [n(32R+32I)][q]
__device__ __align__(16) short g_h[192][256];   // D-GEMM A: [dstk][p-stk] (1/128 folded)
__device__ __align__(16) short g_e[3][256][192];// V-GEMM B: [k][mstk][dstk]
__device__ __align__(16) short g_p[3][128][64]; // low-GEMM B: [k][nout][jstk] (1/128 folded)

static __device__ __forceinline__ short f2bf(float f) {
  unsigned u = __float_as_uint(f);
  unsigned r = (u + 0x7fffu + ((u >> 16) & 1u)) >> 16;  // RNE
  return (short)r;
}
static __device__ __forceinline__ float bf2f(short s) {
  return __uint_as_float(((unsigned)(unsigned short)s) << 16);
}
static __device__ __forceinline__ f32x4 mfma16(bf16x8 a, bf16x8 b, f32x4 c) {
  return __builtin_amdgcn_mfma_f32_16x16x32_bf16(a, b, c, 0, 0, 0);
}

// ---------------- constant-table fill (device fn; merged into gates launch) ----------------
static __device__ void const_fill(int idx) {
  const float C = 6.2831853071795864769f / 128.f;
  if (idx < 8192) {                                  // g_f[n][q]
    int n = idx >> 7, q = idx & 127;
    int j = n & 31;
    float ang = C * (float)((j * q) & 127);
    float v = (n < 32) ? cosf(ang) : -sinf(ang);
    reinterpret_cast<short*>(g_f)[idx] = f2bf(v);
  } else if (idx < 57344) {                          // g_h[d][kk]
    int e = idx - 8192;
    int d = e >> 8, kk = e & 255;
    int r = (d < 96) ? d : d - 96;
    int ifr = (r < 32) ? r : r + 32;
    float ang = C * (float)((ifr * (kk & 127)) & 127);
    float cv = cosf(ang) * (1.f / 128.f), sv = sinf(ang) * (1.f / 128.f);
    float v = (d < 96) ? ((kk < 128) ? cv : sv) : ((kk < 128) ? -sv : cv);
    reinterpret_cast<short*>(g_h)[e] = f2bf(v);
  } else if (idx < 204800) {                         // g_e[k][mm][kk]
    int e = idx - 57344;
    int k = e / 49152; int e2 = e % 49152;
    int mm = e2 / 192, kk = e2 % 192;
    int nk = 32 >> k;
    int r = (kk < 96) ? kk : kk - 96;
    bool allow = (r < nk) || (r >= 32);
    int ifr = (r < 32) ? r : r + 32;
    float ang = C * (float)((ifr * (mm & 127)) & 127);
    float cv = cosf(ang), sv = sinf(ang);
    float v = (mm < 128) ? ((kk < 96) ? cv : -sv) : ((kk < 96) ? sv : cv);
    reinterpret_cast<short*>(g_e)[e] = f2bf(allow ? v : 0.f);
  } else if (idx < 229376) {                         // g_p[k][n][jj]
    int e = idx - 204800;
    int k = e / 8192; int e2 = e % 8192;
    int n = e2 >> 6, jj = e2 & 63;
    int nk = 32 >> k;
    int j = jj & 31;
    bool valid = (j < nk) && (jj < 32 || j > 0);
    float wj = (j == 0) ? (1.f / 128.f) : (2.f / 128.f);
    float ang = C * (float)((j * n) & 127);
    float v = (jj < 32) ? (wj * cosf(ang)) : (-wj * sinf(ang));
    reinterpret_cast<short*>(g_p)[e] = f2bf(valid ? v : 0.f);
  }
}

// ---------------- gates partial, nsplit-way channel split (+ const tail blocks) ----------------
// grid = 8*64*nsplit + 896
__global__ __launch_bounds__(256) void gates_partial_kernel(
    const float* __restrict__ x, const float* __restrict__ Wg,
    float* __restrict__ partial, int nsplit) {
  int bid = blockIdx.x;
  int ngates = 512 * nsplit;
  if (bid >= ngates) {                  // const-table duty
    const_fill((bid - ngates) * 256 + threadIdx.x);
    return;
  }
  int b = bid & 7;
  int tile = (bid >> 3) & 63;
  int cs = bid >> 9;
  int chans = NCHN / nsplit;
  int m = ((tile >> 3) << 4) + (threadIdx.x >> 4);
  int n = ((tile & 7) << 4) + (threadIdx.x & 15);
  float a0 = 0.f, a1 = 0.f, a2 = 0.f;
  const float* xb = x + (size_t)b * NCHN * NPIX;
  for (int c = cs * chans; c < cs * chans + chans; ++c) {
    const float* xc = xb + (size_t)c * NPIX;
    const float* wc = Wg + c * 9;
    #pragma unroll
    for (int dh = -1; dh <= 1; ++dh) {
      int gm = m + dh;
      bool vm = (unsigned)gm < 128u;
      #pragma unroll
      for (int dw = -1; dw <= 1; ++dw) {
        int gn = n + dw;
        float xv = (vm && (unsigned)gn < 128u) ? xc[gm * 128 + gn] : 0.f;
        int tap = (dh + 1) * 3 + (dw + 1);
        a0 = fmaf(xv, wc[tap], a0);
        a1 = fmaf(xv, wc[2304 + tap], a1);
        a2 = fmaf(xv, wc[4608 + tap], a2);
      }
    }
  }
  int pix = m * 128 + n;
  float* pp = partial + (size_t)(cs * 8 + b) * 3 * NPIX;
  pp[pix]            = a0;
  pp[NPIX + pix]     = a1;
  pp[2 * NPIX + pix] = a2;
}

__global__ __launch_bounds__(256) void gates_combine_kernel(
    const float* __restrict__ partial, const float* __restrict__ Bg,
    short* __restrict__ dcoef, int nsplit) {
  int bid = blockIdx.x;                 // 512 = 8b * 64
  int b = bid & 7;
  int px = (bid >> 3) * 256 + threadIdx.x;
  float a0 = Bg[0], a1 = Bg[1], a2 = Bg[2];
  for (int cs = 0; cs < nsplit; ++cs) {
    const float* pp = partial + (size_t)(cs * 8 + b) * 3 * NPIX;
    a0 += pp[px];
    a1 += pp[NPIX + px];
    a2 += pp[2 * NPIX + px];
  }
  float g1 = 2.f / (1.f + expf(-a0));
  float g2 = 2.f / (1.f + expf(-a1));
  float g3 = 2.f / (1.f + expf(-a2));
  int pix = b * NPIX + px;
  dcoef[pix]          = f2bf(g1 - 1.f);
  dcoef[131072 + pix] = f2bf(g2 - g1);
  dcoef[262144 + pix] = f2bf(g3 - g2);
  dcoef[393216 + pix] = f2bf(1.f - g3);
}

// ---------------- fallback gates (if ws too small for partials) ----------------
__global__ __launch_bounds__(256) void gates_kernel(
    const float* __restrict__ x, const float* __restrict__ Wg,
    const float* __restrict__ Bg, short* __restrict__ dcoef) {
  int blk = blockIdx.x;
  if (blk >= 512) {
    const_fill((blk - 512) * 256 + threadIdx.x);
    return;
  }
  int b = blk >> 6;
  int tile = blk & 63;
  int m = ((tile >> 3) << 4) + (threadIdx.x >> 4);
  int n = ((tile & 7) << 4) + (threadIdx.x & 15);
  float a0 = 0.f, a1 = 0.f, a2 = 0.f;
  const float* xb = x + (size_t)b * NCHN * NPIX;
  for (int c = 0; c < NCHN; ++c) {
    const float* xc = xb + (size_t)c * NPIX;
    const float* wc = Wg + c * 9;
    #pragma unroll
    for (int dh = -1; dh <= 1; ++dh) {
      int gm = m + dh;
      bool vm = (unsigned)gm < 128u;
      #pragma unroll
      for (int dw = -1; dw <= 1; ++dw) {
        int gn = n + dw;
        float xv = (vm && (unsigned)gn < 128u) ? xc[gm * 128 + gn] : 0.f;
        int tap = (dh + 1) * 3 + (dw + 1);
        a0 = fmaf(xv, wc[tap], a0);
        a1 = fmaf(xv, wc[2304 + tap], a1);
        a2 = fmaf(xv, wc[4608 + tap], a2);
      }
    }
  }
  a0 += Bg[0]; a1 += Bg[1]; a2 += Bg[2];
  float g1 = 2.f / (1.f + expf(-a0));
  float g2 = 2.f / (1.f + expf(-a1));
  float g3 = 2.f / (1.f + expf(-a2));
  int pix = b * NPIX + m * 128 + n;
  dcoef[pix]          = f2bf(g1 - 1.f);
  dcoef[131072 + pix] = f2bf(g2 - g1);
  dcoef[262144 + pix] = f2bf(g3 - g2);
  dcoef[393216 + pix] = f2bf(1.f - g3);
}

// ---------------- fused spectral kernel: 8 channels of one b per block ----------------
// 512 threads, 60 KB LDS, r14 body, 10 barrier generations per channel.
__global__ __launch_bounds__(512, 2) void fbm_kernel(
    const float* __restrict__ x, const short* __restrict__ dcoef,
    float* __restrict__ out) {
  __shared__ __align__(16) short Xs[16384];      // 32 KB: X bf16 / low plane (aliased)
  __shared__ __align__(16) short WVs[8192];      // 16 KB: W^T / V^T
  __shared__ __align__(16) short Ds2[6144];      // 12 KB: D^T [32n][192dstk]
  char* XsB = reinterpret_cast<char*>(Xs);
  char* PlaneB = XsB;
  char* WsB = reinterpret_cast<char*>(WVs);
  char* DsB = reinterpret_cast<char*>(Ds2);

  int t = threadIdx.x;
  int bid = blockIdx.x;                 // 256 blocks
  int b = bid >> 5;
  int cg = bid & 31;
  size_t img0 = ((size_t)b << 8) + ((size_t)cg << 3);
  int lane = t & 63, w = t >> 6;
  int l15 = lane & 15, l4 = lane >> 4;
  const f32x4 zero = {0.f, 0.f, 0.f, 0.f};

  const short4* d0p = reinterpret_cast<const short4*>(dcoef + ((size_t)b << 14));

  for (int c = 0; c < 8; ++c) {
    // ---- init: oacc = x*(1+d0); stage bf16 X into Xs ----
    f32x4 oaccC[8];
    {
      const f32x4* xv4 = reinterpret_cast<const f32x4*>(x + (img0 + c) * NPIX);
      #pragma unroll
      for (int i = 0; i < 8; ++i) {
        int f = t + i * 512;
        f32x4 xv = __builtin_nontemporal_load(&xv4[f]);
        short4 dv = d0p[f];
        f32x4 dvf = {bf2f(dv.x), bf2f(dv.y), bf2f(dv.z), bf2f(dv.w)};
        oaccC[i] = xv + dvf * xv;
        int row = f >> 5;
        int byte = row * 256 + (((f & 31) * 8) ^ ((row & 7) << 4));
        short4 s;
        s.x = f2bf(xv[0]); s.y = f2bf(xv[1]); s.z = f2bf(xv[2]); s.w = f2bf(xv[3]);
        *reinterpret_cast<short4*>(XsB + byte) = s;
      }
    }
    __syncthreads();

    // ---- P0: W = X*F  (M=p 8 tiles, N=64 4 tiles) ----
    {
      int Ntile = w & 3, Mq = w >> 2;
      int n = Ntile * 16 + l15;
      f32x4 acc[4] = {zero, zero, zero, zero};
      #pragma unroll
      for (int ks = 0; ks < 4; ++ks) {
        int koff = ks * 32 + l4 * 8;
        bf16x8 bf = *reinterpret_cast<const bf16x8*>(&g_f[n][koff]);
        #pragma unroll
        for (int mt = 0; mt < 4; ++mt) {
          int p = (Mq * 4 + mt) * 16 + l15;
          bf16x8 a = *reinterpret_cast<const bf16x8*>(
              XsB + p * 256 + ((koff * 2) ^ ((p & 7) << 4)));
          acc[mt] = mfma16(a, bf, acc[mt]);
        }
      }
      #pragma unroll
      for (int mt = 0; mt < 4; ++mt) {
        int p0 = (Mq * 4 + mt) * 16 + l4 * 4;
        short4 s;
        s.x = f2bf(acc[mt][0]); s.y = f2bf(acc[mt][1]);
        s.z = f2bf(acc[mt][2]); s.w = f2bf(acc[mt][3]);
        *reinterpret_cast<short4*>(WsB + n * 256 + ((p0 * 2) ^ ((n & 7) << 4))) = s;
      }
    }
    __syncthreads();

    // ---- P1: D = Hstk*Wstk  (M=dstk 12 tiles, N=n 2 tiles) ----
    {
      int Ntile = w & 1, Mt3 = w >> 1;
      int n = Ntile * 16 + l15;
      f32x4 acc[3] = {zero, zero, zero};
      #pragma unroll
      for (int ks = 0; ks < 8; ++ks) {
        int koff = ks * 32 + l4 * 8;
        int wrow = n + ((ks >= 4) ? 32 : 0);
        bf16x8 bb = *reinterpret_cast<const bf16x8*>(
            WsB + wrow * 256 + (((koff & 127) * 2) ^ ((wrow & 7) << 4)));
        #pragma unroll
        for (int mt = 0; mt < 3; ++mt) {
          int d = (Mt3 * 3 + mt) * 16 + l15;
          bf16x8 aa = *reinterpret_cast<const bf16x8*>(&g_h[d][koff]);
          acc[mt] = mfma16(aa, bb, acc[mt]);
        }
      }
      #pragma unroll
      for (int mt = 0; mt < 3; ++mt) {
        int d0 = (Mt3 * 3 + mt) * 16 + l4 * 4;
        short4 s;
        s.x = f2bf(acc[mt][0]); s.y = f2bf(acc[mt][1]);
        s.z = f2bf(acc[mt][2]); s.w = f2bf(acc[mt][3]);
        *reinterpret_cast<short4*>(DsB + n * 384 + ((d0 * 2) ^ ((n & 7) << 4))) = s;
      }
    }
    __syncthreads();

    int Mg3 = w >> 2, Ng3 = w & 3;
    for (int k = 0; k < 3; ++k) {
      // ---- P2: V_k = Estk_k*Dstk (M=mstk 16 tiles, N=j 2 tiles) ----
      {
        f32x4 acc[2][2] = {{zero, zero}, {zero, zero}};
        #pragma unroll
        for (int ks = 0; ks < 6; ++ks) {
          int koff = ks * 32 + l4 * 8;
          bf16x8 b0 = *reinterpret_cast<const bf16x8*>(
              DsB + l15 * 384 + ((koff * 2) ^ ((l15 & 7) << 4)));
          int j1 = 16 + l15;
          bf16x8 b1 = *reinterpret_cast<const bf16x8*>(
              DsB + j1 * 384 + ((koff * 2) ^ ((j1 & 7) << 4)));
          #pragma unroll
          for (int mi = 0; mi < 2; ++mi) {
            int mstk = (2 * w + mi) * 16 + l15;
            bf16x8 aa = *reinterpret_cast<const bf16x8*>(&g_e[k][mstk][koff]);
            acc[mi][0] = mfma16(aa, b0, acc[mi][0]);
            acc[mi][1] = mfma16(aa, b1, acc[mi][1]);
          }
        }
        #pragma unroll
        for (int mi = 0; mi < 2; ++mi) {
          #pragma unroll
          for (int ni = 0; ni < 2; ++ni) {
            int j = ni * 16 + l15;
            #pragma unroll
            for (int r = 0; r < 4; ++r) {
              int mstk = (2 * w + mi) * 16 + l4 * 4 + r;
              int m = mstk & 127;
              int jst = ((mstk >> 7) << 5) + j;
              *reinterpret_cast<short*>(WsB + m * 128 + ((jst * 2) ^ ((m & 7) << 4))) =
                  f2bf(acc[mi][ni][r]);
            }
          }
        }
      }
      __syncthreads();
      // ---- P3: low_k = Vstk*P_k -> bf16 Plane (swizzled scatter) ----
      {
        f32x4 acc[4][2] = {{zero, zero}, {zero, zero}, {zero, zero}, {zero, zero}};
        #pragma unroll
        for (int ks = 0; ks < 2; ++ks) {
          int koff = ks * 32 + l4 * 8;
          bf16x8 bfr[2];
          #pragma unroll
          for (int nt = 0; nt < 2; ++nt) {
            int nout = (Ng3 * 2 + nt) * 16 + l15;
            bfr[nt] = *reinterpret_cast<const bf16x8*>(&g_p[k][nout][koff]);
          }
          #pragma unroll
          for (int mt = 0; mt < 4; ++mt) {
            int m = (Mg3 * 4 + mt) * 16 + l15;
            bf16x8 aa = *reinterpret_cast<const bf16x8*>(
                WsB + m * 128 + ((koff * 2) ^ ((m & 7) << 4)));
            acc[mt][0] = mfma16(aa, bfr[0], acc[mt][0]);
            acc[mt][1] = mfma16(aa, bfr[1], acc[mt][1]);
          }
        }
        #pragma unroll
        for (int mt = 0; mt < 4; ++mt) {
          #pragma unroll
          for (int nt = 0; nt < 2; ++nt) {
            int col = (Ng3 * 2 + nt) * 16 + l15;
            #pragma unroll
            for (int r = 0; r < 4; ++r) {
              int row = (Mg3 * 4 + mt) * 16 + l4 * 4 + r;
              int byte = row * 256 + ((col ^ ((row & 7) << 2)) << 1);
              *reinterpret_cast<short*>(PlaneB + byte) = f2bf(acc[mt][nt][r]);
            }
          }
        }
      }
      __syncthreads();
      // ---- fold: LDS plane * global d-plane (L2-hot). NO barrier after:
      // next P2 touches only DsB/WsB; P3(k+1)'s PlaneB overwrite is fenced
      // by the post-P2 barrier. (12 -> 10 generations/channel) ----
      {
        const short4* dk = reinterpret_cast<const short4*>(
            dcoef + (size_t)(k + 1) * 131072 + ((size_t)b << 14));
        #pragma unroll
        for (int i = 0; i < 8; ++i) {
          int f = t + i * 512;
          int row = f >> 5;
          int col = (f & 31) * 4;
          int byte = row * 256 + ((col ^ ((row & 7) << 2)) << 1);
          short4 s = *reinterpret_cast<const short4*>(PlaneB + byte);
          short4 dv = dk[f];
          oaccC[i][0] = fmaf(bf2f(dv.x), bf2f(s.x), oaccC[i][0]);
          oaccC[i][1] = fmaf(bf2f(dv.y), bf2f(s.y), oaccC[i][1]);
          oaccC[i][2] = fmaf(bf2f(dv.z), bf2f(s.z), oaccC[i][2]);
          oaccC[i][3] = fmaf(bf2f(dv.w), bf2f(s.w), oaccC[i][3]);
        }
      }
    }
    __syncthreads();   // Plane (Xs) reads done before next channel's init overwrite

    // ---- coalesced store ----
    f32x4* og4 = reinterpret_cast<f32x4*>(out + (img0 + c) * NPIX);
    #pragma unroll
    for (int i = 0; i < 8; ++i) og4[t + i * 512] = oaccC[i];
  }
}

extern "C" void kernel_launch(void* const* d_in, const int* in_sizes, int n_in,
                              void* d_out, int out_size, void* d_ws, size_t ws_size,
                              hipStream_t stream) {
  const float* x  = (const float*)d_in[0];
  const float* Wg = (const float*)d_in[1];
  const float* Bg = (const float*)d_in[2];
  float* out  = (float*)d_out;
  short* dcoef = (short*)d_ws;                              // 1 MiB: 4 bf16 planes
  float* partial = (float*)((char*)d_ws + (1u << 20));      // up to 12.6 MiB
  size_t need8 = (1u << 20) + (size_t)8 * 8 * 3 * NPIX * 4;  // ~13.6 MiB
  if (ws_size >= need8) {
    gates_partial_kernel<<<4096 + 896, 256, 0, stream>>>(x, Wg, partial, 8);
    gates_combine_kernel<<<512, 256, 0, stream>>>(partial, Bg, dcoef, 8);
  } else if (ws_size >= (size_t)(8u << 20)) {
    gates_partial_kernel<<<2048 + 896, 256, 0, stream>>>(x, Wg, partial, 4);
    gates_combine_kernel<<<512, 256, 0, stream>>>(partial, Bg, dcoef, 4);
  } else {
    gates_kernel<<<1408, 256, 0, stream>>>(x, Wg, Bg, dcoef);
  }
  fbm_kernel<<<256, 512, 0, stream>>>(x, dcoef, out);
}